// Round 16
// baseline (1468.441 us; speedup 1.0000x reference)
//
#include <hip/hip_runtime.h>
#include <hip/hip_bf16.h>

// Session rules (hard-won):
// R6: grid.sync() ~125us on MI355X -- never persistent-coop for a tight recurrence.
// R7: folding w_ih@w_sn into the recurrence fails numerically (0.139, 3x repro).
//     Only value-preserving transformations of the R5 dataflow.
// R8/R9: L2 flushed at kernel boundaries -> ~7MB/step compulsory L3 traffic.
// R9: occupancy clamp strangles VGPR; R10: compiler sinks register preloads (null).
// R12 WIN (2336->1626): global_load_lds weight staging (cold-L2 serial-load latency).
// R13 WIN (1626->1456): y_step 4-way col split. R14: fusion regressed 3rd time -- DEAD.
// R15 WIN (1456->1334): two-phase gates staging + y_step Ws burst.
// R16: gates single-wait form: drop Wi staging (direct global gi loads, 48KB LDS ->
//     3 blocks/CU) -- removes the naked Wi vmcnt(0) drain; holds issued first.

typedef __attribute__((ext_vector_type(8))) short short8;
typedef __attribute__((ext_vector_type(4))) float f32x4;
typedef __hip_bfloat16 bf16_t;

#define BATCH 4096
#define ISZ 64
#define HSZ 256
#define TSZ 64

__device__ __forceinline__ float sigm(float x) { return 1.f / (1.f + __expf(-x)); }
__device__ __forceinline__ float tanh_fast(float x) { return 1.f - 2.f / (1.f + __expf(2.f * x)); }

// load 8 consecutive fp32 and split into two bf16 planes (in-register, RNE)
__device__ __forceinline__ void load_cvt(const float* __restrict__ p, short8& a0, short8& a1) {
  f32x4 u = *reinterpret_cast<const f32x4*>(p);
  f32x4 w = *reinterpret_cast<const f32x4*>(p + 4);
  float x[8] = {u[0], u[1], u[2], u[3], w[0], w[1], w[2], w[3]};
#pragma unroll
  for (int e = 0; e < 8; ++e) {
    bf16_t h0 = __float2bfloat16(x[e]);
    a0[e] = *reinterpret_cast<short*>(&h0);
    bf16_t h1 = __float2bfloat16(x[e] - __bfloat162float(h0));
    a1[e] = *reinterpret_cast<short*>(&h1);
  }
}

__device__ __forceinline__ void async16(const void* g, void* l) {
  __builtin_amdgcn_global_load_lds(
      (const __attribute__((address_space(1))) unsigned int*)g,
      (__attribute__((address_space(3))) unsigned int*)l, 16, 0, 0);
}

// ---------------- spectral norm prep, fp64 (1 block) ----------------
__global__ __launch_bounds__(256) void prep_sn(
    const float* __restrict__ w_lin, const float* __restrict__ u_sn,
    double* __restrict__ w_sn_f64)
{
  __shared__ double v[HSZ];
  __shared__ double red[256];
  __shared__ double Wv[ISZ];
  int t = threadIdx.x;
  double s = 0.0;
  for (int i = 0; i < ISZ; ++i) s += (double)w_lin[i * HSZ + t] * (double)u_sn[i];
  red[t] = s * s;
  __syncthreads();
  for (int off = 128; off > 0; off >>= 1) { if (t < off) red[t] += red[t + off]; __syncthreads(); }
  double nv = sqrt(red[0]);
  v[t] = s / (nv + 1e-12);
  __syncthreads();
  {
    int i = t >> 2, p = t & 3;
    double ps = 0.0;
    for (int k = p * 64; k < p * 64 + 64; ++k) ps += (double)w_lin[i * HSZ + k] * v[k];
    red[t] = ps;
    __syncthreads();
    if ((t & 3) == 0) Wv[i] = red[t] + red[t + 1] + red[t + 2] + red[t + 3];
    __syncthreads();
  }
  red[t] = (t < ISZ) ? Wv[t] * Wv[t] : 0.0;
  __syncthreads();
  for (int off = 128; off > 0; off >>= 1) { if (t < off) red[t] += red[t + off]; __syncthreads(); }
  double nw = sqrt(red[0]);
  double sigma = red[0] / (nw + 1e-12);  // u.(Wv), u = Wv/(|Wv|+eps)
  double inv_sigma = 1.0 / sigma;
  for (int idx = t; idx < ISZ * HSZ; idx += 256)
    w_sn_f64[idx] = (double)w_lin[idx] * inv_sigma;
}

// ---------------- 2-plane split casts (weights + t=0 inputs) ----------------
__global__ __launch_bounds__(256) void split2_f32(
    const float* __restrict__ x, bf16_t* __restrict__ p0, bf16_t* __restrict__ p1, int n)
{
  int i = blockIdx.x * 256 + threadIdx.x;
  if (i < n) {
    float v = x[i];
    bf16_t a = __float2bfloat16(v);
    p0[i] = a;
    p1[i] = __float2bfloat16(v - __bfloat162float(a));
  }
}

__global__ __launch_bounds__(256) void split2_f64(
    const double* __restrict__ x, bf16_t* __restrict__ p0, bf16_t* __restrict__ p1, int n)
{
  int i = blockIdx.x * 256 + threadIdx.x;
  if (i < n) {
    double v = x[i];
    bf16_t a = __float2bfloat16((float)v);
    p0[i] = a;
    p1[i] = __float2bfloat16((float)(v - (double)__bfloat162float(a)));
  }
}

// ---------------- t=0: gi from inputs, h1 = (1-z)*n -> fp32 ----------------
__global__ __launch_bounds__(256) void gru_first(
    const bf16_t* __restrict__ X0, const bf16_t* __restrict__ X1,
    const bf16_t* __restrict__ Wi0, const bf16_t* __restrict__ Wi1,
    const float* __restrict__ b_ih, const float* __restrict__ b_hh,
    float* __restrict__ hF)
{
  const int jb = blockIdx.y;
  const int mw = blockIdx.x * 128 + (threadIdx.x >> 6) * 32;
  const int l = threadIdx.x & 63;
  const int lr = l & 15;
  const int lq = l >> 4;
  const int j = jb * 16 + lr;

  f32x4 accM[2][3], accC[2][3];
#pragma unroll
  for (int mt = 0; mt < 2; ++mt)
#pragma unroll
    for (int g = 0; g < 3; ++g) {
      accM[mt][g] = (f32x4){0.f, 0.f, 0.f, 0.f};
      accC[mt][g] = (f32x4){0.f, 0.f, 0.f, 0.f};
    }

#pragma unroll
  for (int kk = 0; kk < ISZ; kk += 32) {
    short8 a0[2], a1[2];
#pragma unroll
    for (int mt = 0; mt < 2; ++mt) {
      size_t ao = (size_t)(mw + mt * 16 + lr) * ISZ + kk + lq * 8;
      a0[mt] = *reinterpret_cast<const short8*>(X0 + ao);
      a1[mt] = *reinterpret_cast<const short8*>(X1 + ao);
    }
#pragma unroll
    for (int g = 0; g < 3; ++g) {
      size_t bo = (size_t)(g * HSZ + jb * 16 + lr) * ISZ + kk + lq * 8;
      short8 b0 = *reinterpret_cast<const short8*>(Wi0 + bo);
      short8 b1 = *reinterpret_cast<const short8*>(Wi1 + bo);
#pragma unroll
      for (int mt = 0; mt < 2; ++mt) {
        accC[mt][g] = __builtin_amdgcn_mfma_f32_16x16x32_bf16(a0[mt], b1, accC[mt][g], 0, 0, 0);
        accC[mt][g] = __builtin_amdgcn_mfma_f32_16x16x32_bf16(a1[mt], b0, accC[mt][g], 0, 0, 0);
        accM[mt][g] = __builtin_amdgcn_mfma_f32_16x16x32_bf16(a0[mt], b0, accM[mt][g], 0, 0, 0);
      }
    }
  }

  const float brz = b_ih[j] + b_hh[j];
  const float bzz = b_ih[HSZ + j] + b_hh[HSZ + j];
  const float bin = b_ih[2 * HSZ + j];
  const float bhn = b_hh[2 * HSZ + j];

#pragma unroll
  for (int mt = 0; mt < 2; ++mt) {
#pragma unroll
    for (int q = 0; q < 4; ++q) {
      int b = mw + mt * 16 + lq * 4 + q;
      float r = sigm(accM[mt][0][q] + accC[mt][0][q] + brz);
      float z = sigm(accM[mt][1][q] + accC[mt][1][q] + bzz);
      float n = tanh_fast(accM[mt][2][q] + accC[mt][2][q] + bin + r * bhn);
      hF[(size_t)b * HSZ + j] = (1.f - z) * n;
    }
  }
}

// ---------------- gates step (t>=1): single-wait staged form ----------------
// Grid (BATCH/128, 16); block 256 = 4 waves; wave = 32 rows (2 mt) x 16 j.
// LDS: lWh only (48 KB -> 3 blocks/CU). Issue all 12 Wh DMAs + holds, compute gi
// (Wi/yprev direct global loads overlap the Wh stream), then ONE vmcnt(0)+barrier,
// then gh. XOR swizzle on Wh source+read (rule #21). Identical per-acc MFMA order
// and operand values as R15 -> bit-identical output.
__global__ __launch_bounds__(256) void gru_gates(
    const float* __restrict__ yprev,  // out + (t-1)*BATCH*64
    const float* __restrict__ hF,     // [BATCH, 256] fp32
    const bf16_t* __restrict__ Wi0, const bf16_t* __restrict__ Wi1,
    const bf16_t* __restrict__ Wh0, const bf16_t* __restrict__ Wh1,
    const float* __restrict__ b_ih, const float* __restrict__ b_hh,
    float* __restrict__ hFo)
{
  __shared__ __align__(16) short lWh[96 * 256];  // 48 KB

  const int jb = blockIdx.y;
  const int tid = threadIdx.x;
  const int wid = tid >> 6;
  const int mw = blockIdx.x * 128 + wid * 32;
  const int l = tid & 63;
  const int lr = l & 15;
  const int lq = l >> 4;
  const int j = jb * 16 + lr;

  // hold loads first (retire while everything else streams)
  float hold_[2][4];
#pragma unroll
  for (int mt = 0; mt < 2; ++mt)
#pragma unroll
    for (int q = 0; q < 4; ++q)
      hold_[mt][q] = hF[(size_t)(mw + mt * 16 + lq * 4 + q) * HSZ + j];

  // ---- issue all Wh DMAs (12 x 4KB); linear LDS dest, swizzled source
#pragma unroll
  for (int i = 0; i < 12; ++i) {
    int L = i * 4096 + tid * 16;
    int R = L >> 9, c16 = L & 511;
    int csrc = c16 ^ ((R & 7) << 4);
    int g = R >> 5, p = (R >> 4) & 1, jr = R & 15;
    const bf16_t* srcrow = (p ? Wh1 : Wh0) + (size_t)(g * HSZ + jb * 16 + jr) * HSZ;
    async16((const char*)srcrow + csrc, (char*)lWh + i * 4096 + wid * 1024);
  }

  f32x4 accM[2][4], accC[2][4];
#pragma unroll
  for (int mt = 0; mt < 2; ++mt)
#pragma unroll
    for (int g = 0; g < 4; ++g) {
      accM[mt][g] = (f32x4){0.f, 0.f, 0.f, 0.f};
      accC[mt][g] = (f32x4){0.f, 0.f, 0.f, 0.f};
    }

  // ---- gi: x = split2(yprev) @ w_ih.T (K=64), Wi direct from global;
  //      overlaps the in-flight Wh DMA stream
#pragma unroll
  for (int c = 0; c < 2; ++c) {
    short8 a0[2], a1[2];
#pragma unroll
    for (int mt = 0; mt < 2; ++mt)
      load_cvt(yprev + (size_t)(mw + mt * 16 + lr) * ISZ + c * 32 + lq * 8, a0[mt], a1[mt]);
#pragma unroll
    for (int g = 0; g < 3; ++g) {
      size_t bo = (size_t)(g * HSZ + jb * 16 + lr) * ISZ + c * 32 + lq * 8;
      short8 b0 = *reinterpret_cast<const short8*>(Wi0 + bo);
      short8 b1 = *reinterpret_cast<const short8*>(Wi1 + bo);
#pragma unroll
      for (int mt = 0; mt < 2; ++mt) {
        accC[mt][g] = __builtin_amdgcn_mfma_f32_16x16x32_bf16(a0[mt], b1, accC[mt][g], 0, 0, 0);
        accC[mt][g] = __builtin_amdgcn_mfma_f32_16x16x32_bf16(a1[mt], b0, accC[mt][g], 0, 0, 0);
        accM[mt][g] = __builtin_amdgcn_mfma_f32_16x16x32_bf16(a0[mt], b0, accM[mt][g], 0, 0, 0);
      }
    }
  }

  // ---- single wait: all Wh staged (gi's loads already consumed)
  asm volatile("s_waitcnt vmcnt(0)" ::: "memory");
  __builtin_amdgcn_s_barrier();

  auto whf = [&](int g, int p, int c) -> short8 {
    int R = (g * 2 + p) * 16 + lr;
    int byte = R * 512 + ((c * 64 + lq * 16) ^ ((lr & 7) << 4));
    return *reinterpret_cast<const short8*>((const char*)lWh + byte);
  };

  // ---- gh: h = split2(hF) @ w_hh.T (K=256); gates 0,1 -> cols 0,1; gate 2 -> col 3
#pragma unroll
  for (int c = 0; c < 8; ++c) {
    short8 a0[2], a1[2];
#pragma unroll
    for (int mt = 0; mt < 2; ++mt)
      load_cvt(hF + (size_t)(mw + mt * 16 + lr) * HSZ + c * 32 + lq * 8, a0[mt], a1[mt]);
#pragma unroll
    for (int g = 0; g < 3; ++g) {
      const int tgt = (g == 2) ? 3 : g;
      short8 b0 = whf(g, 0, c);
      short8 b1 = whf(g, 1, c);
#pragma unroll
      for (int mt = 0; mt < 2; ++mt) {
        accC[mt][tgt] = __builtin_amdgcn_mfma_f32_16x16x32_bf16(a0[mt], b1, accC[mt][tgt], 0, 0, 0);
        accC[mt][tgt] = __builtin_amdgcn_mfma_f32_16x16x32_bf16(a1[mt], b0, accC[mt][tgt], 0, 0, 0);
        accM[mt][tgt] = __builtin_amdgcn_mfma_f32_16x16x32_bf16(a0[mt], b0, accM[mt][tgt], 0, 0, 0);
      }
    }
  }

  const float brz = b_ih[j] + b_hh[j];
  const float bzz = b_ih[HSZ + j] + b_hh[HSZ + j];
  const float bin = b_ih[2 * HSZ + j];
  const float bhn = b_hh[2 * HSZ + j];

#pragma unroll
  for (int mt = 0; mt < 2; ++mt) {
#pragma unroll
    for (int q = 0; q < 4; ++q) {
      int b = mw + mt * 16 + lq * 4 + q;  // C/D: row=(lane>>4)*4+reg, col=lane&15
      float rpre = accM[mt][0][q] + accC[mt][0][q] + brz;
      float zpre = accM[mt][1][q] + accC[mt][1][q] + bzz;
      float inn  = accM[mt][2][q] + accC[mt][2][q] + bin;
      float hnn  = accM[mt][3][q] + accC[mt][3][q] + bhn;
      float r = sigm(rpre);
      float z = sigm(zpre);
      float n = tanh_fast(inn + r * hnn);
      double hv = (double)((1.f - z) * n) + (double)z * (double)hold_[mt][q];
      hFo[(size_t)b * HSZ + j] = (float)hv;
    }
  }
}

// ---------------- y_step: out[t] = split2(hF) @ w_sn.T + b_lin ----------------
// Grid (BATCH/16, 4) one-wave blocks; wave = 16 rows x one 16-col tile (nt).
// Ws slice (16 KB) staged via global_load_lds burst; XOR-swizzled src+read.
__global__ __launch_bounds__(64) void y_step(
    const float* __restrict__ hF,
    const bf16_t* __restrict__ Ws0, const bf16_t* __restrict__ Ws1,
    const float* __restrict__ b_lin,
    float* __restrict__ yout)  // out + t*BATCH*64
{
  __shared__ __align__(16) short lWs[2 * 16 * 256];  // 16 KB

  const int mw = blockIdx.x * 16;
  const int nt = blockIdx.y;
  const int l = threadIdx.x;
  const int lr = l & 15;
  const int lq = l >> 4;

  // stage: 16 x 1KB; linear LDS dest, swizzled source
#pragma unroll
  for (int i = 0; i < 16; ++i) {
    int L = i * 1024 + l * 16;
    int plane = L >> 13;
    int R = (L >> 9) & 15;
    int c16 = L & 511;
    int csrc = c16 ^ ((R & 7) << 4);
    const bf16_t* srcrow = (plane ? Ws1 : Ws0) + (size_t)(nt * 16 + R) * HSZ;
    async16((const char*)srcrow + csrc, (char*)lWs + i * 1024);
  }
  asm volatile("s_waitcnt vmcnt(0)" ::: "memory");

  f32x4 accM = (f32x4){0.f, 0.f, 0.f, 0.f};
  f32x4 accC = (f32x4){0.f, 0.f, 0.f, 0.f};

#pragma unroll
  for (int c = 0; c < 8; ++c) {
    short8 a0, a1;
    load_cvt(hF + (size_t)(mw + lr) * HSZ + c * 32 + lq * 8, a0, a1);
    int byte = lr * 512 + ((c * 64 + lq * 16) ^ ((lr & 7) << 4));
    short8 b0 = *reinterpret_cast<const short8*>((const char*)lWs + byte);
    short8 b1 = *reinterpret_cast<const short8*>((const char*)lWs + 8192 + byte);
    accC = __builtin_amdgcn_mfma_f32_16x16x32_bf16(a0, b1, accC, 0, 0, 0);
    accC = __builtin_amdgcn_mfma_f32_16x16x32_bf16(a1, b0, accC, 0, 0, 0);
    accM = __builtin_amdgcn_mfma_f32_16x16x32_bf16(a0, b0, accM, 0, 0, 0);
  }

  const int o = nt * 16 + lr;
  const float bl = b_lin[o];
#pragma unroll
  for (int q = 0; q < 4; ++q) {
    size_t row = mw + lq * 4 + q;
    yout[row * 64 + o] = accM[q] + accC[q] + bl;
  }
}

// ---------------- BatchNorm: two-stage stats + normalize ----------------
__global__ __launch_bounds__(256) void bn_part(const float* __restrict__ Y,
                                               double* __restrict__ psum,
                                               double* __restrict__ psum2)
{
  int t = blockIdx.x;
  int chunk = blockIdx.y;
  int o = threadIdx.x & 63, rg = threadIdx.x >> 6;
  const float* Yt = Y + (size_t)t * BATCH * 64;
  int b0 = chunk * 256;
  double s = 0.0, s2 = 0.0;
  for (int b = b0 + rg; b < b0 + 256; b += 4) {
    double v = (double)Yt[(size_t)b * 64 + o];
    s += v;
    s2 += v * v;
  }
  __shared__ double ls[4][64], ls2[4][64];
  ls[rg][o] = s;
  ls2[rg][o] = s2;
  __syncthreads();
  if (rg == 0) {
    s = ls[0][o] + ls[1][o] + ls[2][o] + ls[3][o];
    s2 = ls2[0][o] + ls2[1][o] + ls2[2][o] + ls2[3][o];
    size_t pi = ((size_t)t * 16 + chunk) * 64 + o;
    psum[pi] = s;
    psum2[pi] = s2;
  }
}

__global__ __launch_bounds__(64) void bn_final(const double* __restrict__ psum,
                                               const double* __restrict__ psum2,
                                               float* __restrict__ mean,
                                               float* __restrict__ istd)
{
  int t = blockIdx.x;
  int o = threadIdx.x;
  double s = 0.0, s2 = 0.0;
  for (int c = 0; c < 16; ++c) {
    size_t pi = ((size_t)t * 16 + c) * 64 + o;
    s += psum[pi];
    s2 += psum2[pi];
  }
  double m = s * (1.0 / BATCH);
  double var = s2 * (1.0 / BATCH) - m * m;
  mean[t * 64 + o] = (float)m;
  istd[t * 64 + o] = (float)(1.0 / sqrt(var + 1e-5));
}

__global__ __launch_bounds__(256) void bn_norm(float* __restrict__ Y,
                                               const float* __restrict__ mean,
                                               const float* __restrict__ istd, int n4)
{
  for (int i = blockIdx.x * 256 + threadIdx.x; i < n4; i += gridDim.x * 256) {
    f32x4 v = reinterpret_cast<f32x4*>(Y)[i];
    int base = i * 4;
    int o = base & 63;
    int t = base >> 18;  // / (BATCH*64)
    const float* mr = mean + t * 64;
    const float* ir = istd + t * 64;
#pragma unroll
    for (int e = 0; e < 4; ++e) v[e] = (v[e] - mr[o + e]) * ir[o + e];
    reinterpret_cast<f32x4*>(Y)[i] = v;
  }
}

extern "C" void kernel_launch(void* const* d_in, const int* in_sizes, int n_in,
                              void* d_out, int out_size, void* d_ws, size_t ws_size,
                              hipStream_t stream)
{
  const float* inputs = (const float*)d_in[0];
  const float* w_ih = (const float*)d_in[1];
  const float* w_hh = (const float*)d_in[2];
  const float* b_ih = (const float*)d_in[3];
  const float* b_hh = (const float*)d_in[4];
  const float* w_lin = (const float*)d_in[5];
  const float* b_lin = (const float*)d_in[6];
  const float* u_sn = (const float*)d_in[7];
  float* out = (float*)d_out;

  const size_t BH = (size_t)BATCH * HSZ;
  const size_t BI = (size_t)BATCH * ISZ;

  char* ws = (char*)d_ws;
  size_t off = 0;
  auto alloc = [&](size_t bytes) -> void* {
    void* p = ws + off;
    off += (bytes + 255) & ~(size_t)255;
    return p;
  };
  double* w_sn_f64 = (double*)alloc((size_t)ISZ * HSZ * 8);
  bf16_t* Wi0 = (bf16_t*)alloc((size_t)3 * HSZ * ISZ * 2);
  bf16_t* Wi1 = (bf16_t*)alloc((size_t)3 * HSZ * ISZ * 2);
  bf16_t* Wh0 = (bf16_t*)alloc((size_t)3 * HSZ * HSZ * 2);
  bf16_t* Wh1 = (bf16_t*)alloc((size_t)3 * HSZ * HSZ * 2);
  bf16_t* Ws0 = (bf16_t*)alloc((size_t)ISZ * HSZ * 2);
  bf16_t* Ws1 = (bf16_t*)alloc((size_t)ISZ * HSZ * 2);
  bf16_t* X0 = (bf16_t*)alloc(BI * 2);
  bf16_t* X1 = (bf16_t*)alloc(BI * 2);
  float* hFA = (float*)alloc(BH * 4);
  float* hFB = (float*)alloc(BH * 4);
  double* psum = (double*)alloc((size_t)TSZ * 16 * 64 * 8);
  double* psum2 = (double*)alloc((size_t)TSZ * 16 * 64 * 8);
  float* meanb = (float*)alloc(TSZ * 64 * 4);
  float* istdb = (float*)alloc(TSZ * 64 * 4);
  if (off > ws_size) return;

  prep_sn<<<1, 256, 0, stream>>>(w_lin, u_sn, w_sn_f64);
  split2_f32<<<(3 * HSZ * ISZ + 255) / 256, 256, 0, stream>>>(w_ih, Wi0, Wi1, 3 * HSZ * ISZ);
  split2_f32<<<(3 * HSZ * HSZ + 255) / 256, 256, 0, stream>>>(w_hh, Wh0, Wh1, 3 * HSZ * HSZ);
  split2_f64<<<(ISZ * HSZ + 255) / 256, 256, 0, stream>>>(w_sn_f64, Ws0, Ws1, ISZ * HSZ);
  split2_f32<<<((int)BI + 255) / 256, 256, 0, stream>>>(inputs, X0, X1, (int)BI);

  // t = 0: h_0 from inputs, then y_0
  gru_first<<<dim3(BATCH / 128, 16), 256, 0, stream>>>(X0, X1, Wi0, Wi1, b_ih, b_hh, hFA);
  y_step<<<dim3(BATCH / 16, 4), 64, 0, stream>>>(hFA, Ws0, Ws1, b_lin, out);

  float* hin = hFA;
  float* hout = hFB;
  for (int t = 1; t < TSZ; ++t) {
    gru_gates<<<dim3(BATCH / 128, 16), 256, 0, stream>>>(
        out + (size_t)(t - 1) * BATCH * 64, hin,
        Wi0, Wi1, Wh0, Wh1, b_ih, b_hh, hout);
    y_step<<<dim3(BATCH / 16, 4), 64, 0, stream>>>(hout, Ws0, Ws1, b_lin,
                                                   out + (size_t)t * BATCH * 64);
    float* tm = hin; hin = hout; hout = tm;
  }

  bn_part<<<dim3(TSZ, 16), 256, 0, stream>>>(out, psum, psum2);
  bn_final<<<TSZ, 64, 0, stream>>>(psum, psum2, meanb, istdb);
  bn_norm<<<2048, 256, 0, stream>>>(out, meanb, istdb, TSZ * BATCH * 64 / 4);
}

// Round 17
// 1467.165 us; speedup vs baseline: 1.0009x; 1.0009x over previous
//
#include <hip/hip_runtime.h>
#include <hip/hip_bf16.h>

// Session rules (hard-won):
// R6: grid.sync() ~125us on MI355X -- never persistent-coop for a tight recurrence.
// R7: folding w_ih@w_sn into the recurrence fails numerically (0.139, 3x repro).
//     Only value-preserving transformations of the R5 dataflow.
// R8/R9: L2 flushed at kernel boundaries -> ~7MB/step compulsory L3 traffic.
// R10: compiler sinks register preloads unless pinned (asm volatile "+v").
// R12 WIN (2336->1626): global_load_lds weight staging. R13 WIN (->1456): y_step
//     4-way col split. R14: fusion regressed 3rd time -- DEAD.
// R15 WIN (1456->1334): two-phase gates staging + y_step Ws burst.
// R16 REGRESS (1468): gi loads issued AFTER Wh DMAs -> compiler's wait for them
//     drained the whole DMA stream (vmcnt waits are ordered, m135).
// R17: gi operands preloaded to regs BEFORE the DMAs (pinned), so gi overlaps the
//     Wh stream; no Wi LDS (48KB -> 3 blocks/CU). Bit-identical values/order.

typedef __attribute__((ext_vector_type(8))) short short8;
typedef __attribute__((ext_vector_type(4))) float f32x4;
typedef __hip_bfloat16 bf16_t;

#define BATCH 4096
#define ISZ 64
#define HSZ 256
#define TSZ 64

__device__ __forceinline__ float sigm(float x) { return 1.f / (1.f + __expf(-x)); }
__device__ __forceinline__ float tanh_fast(float x) { return 1.f - 2.f / (1.f + __expf(2.f * x)); }

// split 8 fp32 (two f32x4) into two bf16 planes (in-register, RNE)
__device__ __forceinline__ void cvt8(const f32x4& u, const f32x4& w, short8& a0, short8& a1) {
  float x[8] = {u[0], u[1], u[2], u[3], w[0], w[1], w[2], w[3]};
#pragma unroll
  for (int e = 0; e < 8; ++e) {
    bf16_t h0 = __float2bfloat16(x[e]);
    a0[e] = *reinterpret_cast<short*>(&h0);
    bf16_t h1 = __float2bfloat16(x[e] - __bfloat162float(h0));
    a1[e] = *reinterpret_cast<short*>(&h1);
  }
}

__device__ __forceinline__ void load_cvt(const float* __restrict__ p, short8& a0, short8& a1) {
  f32x4 u = *reinterpret_cast<const f32x4*>(p);
  f32x4 w = *reinterpret_cast<const f32x4*>(p + 4);
  cvt8(u, w, a0, a1);
}

__device__ __forceinline__ void async16(const void* g, void* l) {
  __builtin_amdgcn_global_load_lds(
      (const __attribute__((address_space(1))) unsigned int*)g,
      (__attribute__((address_space(3))) unsigned int*)l, 16, 0, 0);
}

// ---------------- spectral norm prep, fp64 (1 block) ----------------
__global__ __launch_bounds__(256) void prep_sn(
    const float* __restrict__ w_lin, const float* __restrict__ u_sn,
    double* __restrict__ w_sn_f64)
{
  __shared__ double v[HSZ];
  __shared__ double red[256];
  __shared__ double Wv[ISZ];
  int t = threadIdx.x;
  double s = 0.0;
  for (int i = 0; i < ISZ; ++i) s += (double)w_lin[i * HSZ + t] * (double)u_sn[i];
  red[t] = s * s;
  __syncthreads();
  for (int off = 128; off > 0; off >>= 1) { if (t < off) red[t] += red[t + off]; __syncthreads(); }
  double nv = sqrt(red[0]);
  v[t] = s / (nv + 1e-12);
  __syncthreads();
  {
    int i = t >> 2, p = t & 3;
    double ps = 0.0;
    for (int k = p * 64; k < p * 64 + 64; ++k) ps += (double)w_lin[i * HSZ + k] * v[k];
    red[t] = ps;
    __syncthreads();
    if ((t & 3) == 0) Wv[i] = red[t] + red[t + 1] + red[t + 2] + red[t + 3];
    __syncthreads();
  }
  red[t] = (t < ISZ) ? Wv[t] * Wv[t] : 0.0;
  __syncthreads();
  for (int off = 128; off > 0; off >>= 1) { if (t < off) red[t] += red[t + off]; __syncthreads(); }
  double nw = sqrt(red[0]);
  double sigma = red[0] / (nw + 1e-12);  // u.(Wv), u = Wv/(|Wv|+eps)
  double inv_sigma = 1.0 / sigma;
  for (int idx = t; idx < ISZ * HSZ; idx += 256)
    w_sn_f64[idx] = (double)w_lin[idx] * inv_sigma;
}

// ---------------- 2-plane split casts (weights + t=0 inputs) ----------------
__global__ __launch_bounds__(256) void split2_f32(
    const float* __restrict__ x, bf16_t* __restrict__ p0, bf16_t* __restrict__ p1, int n)
{
  int i = blockIdx.x * 256 + threadIdx.x;
  if (i < n) {
    float v = x[i];
    bf16_t a = __float2bfloat16(v);
    p0[i] = a;
    p1[i] = __float2bfloat16(v - __bfloat162float(a));
  }
}

__global__ __launch_bounds__(256) void split2_f64(
    const double* __restrict__ x, bf16_t* __restrict__ p0, bf16_t* __restrict__ p1, int n)
{
  int i = blockIdx.x * 256 + threadIdx.x;
  if (i < n) {
    double v = x[i];
    bf16_t a = __float2bfloat16((float)v);
    p0[i] = a;
    p1[i] = __float2bfloat16((float)(v - (double)__bfloat162float(a)));
  }
}

// ---------------- t=0: gi from inputs, h1 = (1-z)*n -> fp32 ----------------
__global__ __launch_bounds__(256) void gru_first(
    const bf16_t* __restrict__ X0, const bf16_t* __restrict__ X1,
    const bf16_t* __restrict__ Wi0, const bf16_t* __restrict__ Wi1,
    const float* __restrict__ b_ih, const float* __restrict__ b_hh,
    float* __restrict__ hF)
{
  const int jb = blockIdx.y;
  const int mw = blockIdx.x * 128 + (threadIdx.x >> 6) * 32;
  const int l = threadIdx.x & 63;
  const int lr = l & 15;
  const int lq = l >> 4;
  const int j = jb * 16 + lr;

  f32x4 accM[2][3], accC[2][3];
#pragma unroll
  for (int mt = 0; mt < 2; ++mt)
#pragma unroll
    for (int g = 0; g < 3; ++g) {
      accM[mt][g] = (f32x4){0.f, 0.f, 0.f, 0.f};
      accC[mt][g] = (f32x4){0.f, 0.f, 0.f, 0.f};
    }

#pragma unroll
  for (int kk = 0; kk < ISZ; kk += 32) {
    short8 a0[2], a1[2];
#pragma unroll
    for (int mt = 0; mt < 2; ++mt) {
      size_t ao = (size_t)(mw + mt * 16 + lr) * ISZ + kk + lq * 8;
      a0[mt] = *reinterpret_cast<const short8*>(X0 + ao);
      a1[mt] = *reinterpret_cast<const short8*>(X1 + ao);
    }
#pragma unroll
    for (int g = 0; g < 3; ++g) {
      size_t bo = (size_t)(g * HSZ + jb * 16 + lr) * ISZ + kk + lq * 8;
      short8 b0 = *reinterpret_cast<const short8*>(Wi0 + bo);
      short8 b1 = *reinterpret_cast<const short8*>(Wi1 + bo);
#pragma unroll
      for (int mt = 0; mt < 2; ++mt) {
        accC[mt][g] = __builtin_amdgcn_mfma_f32_16x16x32_bf16(a0[mt], b1, accC[mt][g], 0, 0, 0);
        accC[mt][g] = __builtin_amdgcn_mfma_f32_16x16x32_bf16(a1[mt], b0, accC[mt][g], 0, 0, 0);
        accM[mt][g] = __builtin_amdgcn_mfma_f32_16x16x32_bf16(a0[mt], b0, accM[mt][g], 0, 0, 0);
      }
    }
  }

  const float brz = b_ih[j] + b_hh[j];
  const float bzz = b_ih[HSZ + j] + b_hh[HSZ + j];
  const float bin = b_ih[2 * HSZ + j];
  const float bhn = b_hh[2 * HSZ + j];

#pragma unroll
  for (int mt = 0; mt < 2; ++mt) {
#pragma unroll
    for (int q = 0; q < 4; ++q) {
      int b = mw + mt * 16 + lq * 4 + q;
      float r = sigm(accM[mt][0][q] + accC[mt][0][q] + brz);
      float z = sigm(accM[mt][1][q] + accC[mt][1][q] + bzz);
      float n = tanh_fast(accM[mt][2][q] + accC[mt][2][q] + bin + r * bhn);
      hF[(size_t)b * HSZ + j] = (1.f - z) * n;
    }
  }
}

// ---------------- gates step (t>=1): preload-then-DMA overlapped form ----------------
// Grid (BATCH/128, 16); block 256 = 4 waves; wave = 32 rows (2 mt) x 16 j.
// Order: (1) hold + yprev + Wi loads into REGISTERS (pinned -- cannot sink);
// (2) issue 12 Wh DMAs; (3) gi from regs (compiler waits only on the older reg
// loads -> Wh stream stays in flight); (4) one vmcnt(0)+barrier; (5) gh from LDS.
// LDS = lWh only (48KB -> 3 blocks/CU). Values + MFMA order identical to R15.
__global__ __launch_bounds__(256) void gru_gates(
    const float* __restrict__ yprev,  // out + (t-1)*BATCH*64
    const float* __restrict__ hF,     // [BATCH, 256] fp32
    const bf16_t* __restrict__ Wi0, const bf16_t* __restrict__ Wi1,
    const bf16_t* __restrict__ Wh0, const bf16_t* __restrict__ Wh1,
    const float* __restrict__ b_ih, const float* __restrict__ b_hh,
    float* __restrict__ hFo)
{
  __shared__ __align__(16) short lWh[96 * 256];  // 48 KB

  const int jb = blockIdx.y;
  const int tid = threadIdx.x;
  const int wid = tid >> 6;
  const int mw = blockIdx.x * 128 + wid * 32;
  const int l = tid & 63;
  const int lr = l & 15;
  const int lq = l >> 4;
  const int j = jb * 16 + lr;

  // ---- (1) preload gi operands + holds into registers
  float hold_[2][4];
#pragma unroll
  for (int mt = 0; mt < 2; ++mt)
#pragma unroll
    for (int q = 0; q < 4; ++q)
      hold_[mt][q] = hF[(size_t)(mw + mt * 16 + lq * 4 + q) * HSZ + j];

  f32x4 ypA[2][2], ypB[2][2];  // [mt][c]
#pragma unroll
  for (int mt = 0; mt < 2; ++mt)
#pragma unroll
    for (int c = 0; c < 2; ++c) {
      const float* p = yprev + (size_t)(mw + mt * 16 + lr) * ISZ + c * 32 + lq * 8;
      ypA[mt][c] = *reinterpret_cast<const f32x4*>(p);
      ypB[mt][c] = *reinterpret_cast<const f32x4*>(p + 4);
    }

  short8 wiB0[3][2], wiB1[3][2];  // [g][c]
#pragma unroll
  for (int g = 0; g < 3; ++g)
#pragma unroll
    for (int c = 0; c < 2; ++c) {
      size_t bo = (size_t)(g * HSZ + jb * 16 + lr) * ISZ + c * 32 + lq * 8;
      wiB0[g][c] = *reinterpret_cast<const short8*>(Wi0 + bo);
      wiB1[g][c] = *reinterpret_cast<const short8*>(Wi1 + bo);
    }

  // pin: force materialization before the DMA issues (rule #17 / R10 lesson)
#pragma unroll
  for (int mt = 0; mt < 2; ++mt)
#pragma unroll
    for (int c = 0; c < 2; ++c) {
      asm volatile("" : "+v"(ypA[mt][c]), "+v"(ypB[mt][c]));
    }
#pragma unroll
  for (int g = 0; g < 3; ++g)
#pragma unroll
    for (int c = 0; c < 2; ++c) {
      asm volatile("" : "+v"(wiB0[g][c]), "+v"(wiB1[g][c]));
    }
#pragma unroll
  for (int mt = 0; mt < 2; ++mt)
#pragma unroll
    for (int q = 0; q < 4; ++q) asm volatile("" : "+v"(hold_[mt][q]));

  // ---- (2) issue all Wh DMAs (12 x 4KB); linear LDS dest, swizzled source
#pragma unroll
  for (int i = 0; i < 12; ++i) {
    int L = i * 4096 + tid * 16;
    int R = L >> 9, c16 = L & 511;
    int csrc = c16 ^ ((R & 7) << 4);
    int g = R >> 5, p = (R >> 4) & 1, jr = R & 15;
    const bf16_t* srcrow = (p ? Wh1 : Wh0) + (size_t)(g * HSZ + jb * 16 + jr) * HSZ;
    async16((const char*)srcrow + csrc, (char*)lWh + i * 4096 + wid * 1024);
  }

  f32x4 accM[2][4], accC[2][4];
#pragma unroll
  for (int mt = 0; mt < 2; ++mt)
#pragma unroll
    for (int g = 0; g < 4; ++g) {
      accM[mt][g] = (f32x4){0.f, 0.f, 0.f, 0.f};
      accC[mt][g] = (f32x4){0.f, 0.f, 0.f, 0.f};
    }

  // ---- (3) gi from registers; overlaps the in-flight Wh stream
#pragma unroll
  for (int c = 0; c < 2; ++c) {
    short8 a0[2], a1[2];
#pragma unroll
    for (int mt = 0; mt < 2; ++mt) cvt8(ypA[mt][c], ypB[mt][c], a0[mt], a1[mt]);
#pragma unroll
    for (int g = 0; g < 3; ++g) {
#pragma unroll
      for (int mt = 0; mt < 2; ++mt) {
        accC[mt][g] = __builtin_amdgcn_mfma_f32_16x16x32_bf16(a0[mt], wiB1[g][c], accC[mt][g], 0, 0, 0);
        accC[mt][g] = __builtin_amdgcn_mfma_f32_16x16x32_bf16(a1[mt], wiB0[g][c], accC[mt][g], 0, 0, 0);
        accM[mt][g] = __builtin_amdgcn_mfma_f32_16x16x32_bf16(a0[mt], wiB0[g][c], accM[mt][g], 0, 0, 0);
      }
    }
  }

  // ---- (4) single wait: all Wh staged
  asm volatile("s_waitcnt vmcnt(0)" ::: "memory");
  __builtin_amdgcn_s_barrier();

  auto whf = [&](int g, int p, int c) -> short8 {
    int R = (g * 2 + p) * 16 + lr;
    int byte = R * 512 + ((c * 64 + lq * 16) ^ ((lr & 7) << 4));
    return *reinterpret_cast<const short8*>((const char*)lWh + byte);
  };

  // ---- (5) gh: h = split2(hF) @ w_hh.T (K=256); gates 0,1 -> cols 0,1; gate 2 -> col 3
#pragma unroll
  for (int c = 0; c < 8; ++c) {
    short8 a0[2], a1[2];
#pragma unroll
    for (int mt = 0; mt < 2; ++mt)
      load_cvt(hF + (size_t)(mw + mt * 16 + lr) * HSZ + c * 32 + lq * 8, a0[mt], a1[mt]);
#pragma unroll
    for (int g = 0; g < 3; ++g) {
      const int tgt = (g == 2) ? 3 : g;
      short8 b0 = whf(g, 0, c);
      short8 b1 = whf(g, 1, c);
#pragma unroll
      for (int mt = 0; mt < 2; ++mt) {
        accC[mt][tgt] = __builtin_amdgcn_mfma_f32_16x16x32_bf16(a0[mt], b1, accC[mt][tgt], 0, 0, 0);
        accC[mt][tgt] = __builtin_amdgcn_mfma_f32_16x16x32_bf16(a1[mt], b0, accC[mt][tgt], 0, 0, 0);
        accM[mt][tgt] = __builtin_amdgcn_mfma_f32_16x16x32_bf16(a0[mt], b0, accM[mt][tgt], 0, 0, 0);
      }
    }
  }

  const float brz = b_ih[j] + b_hh[j];
  const float bzz = b_ih[HSZ + j] + b_hh[HSZ + j];
  const float bin = b_ih[2 * HSZ + j];
  const float bhn = b_hh[2 * HSZ + j];

#pragma unroll
  for (int mt = 0; mt < 2; ++mt) {
#pragma unroll
    for (int q = 0; q < 4; ++q) {
      int b = mw + mt * 16 + lq * 4 + q;  // C/D: row=(lane>>4)*4+reg, col=lane&15
      float rpre = accM[mt][0][q] + accC[mt][0][q] + brz;
      float zpre = accM[mt][1][q] + accC[mt][1][q] + bzz;
      float inn  = accM[mt][2][q] + accC[mt][2][q] + bin;
      float hnn  = accM[mt][3][q] + accC[mt][3][q] + bhn;
      float r = sigm(rpre);
      float z = sigm(zpre);
      float n = tanh_fast(inn + r * hnn);
      double hv = (double)((1.f - z) * n) + (double)z * (double)hold_[mt][q];
      hFo[(size_t)b * HSZ + j] = (float)hv;
    }
  }
}

// ---------------- y_step: out[t] = split2(hF) @ w_sn.T + b_lin ----------------
// Grid (BATCH/16, 4) one-wave blocks; wave = 16 rows x one 16-col tile (nt).
// Ws slice (16 KB) staged via global_load_lds burst; XOR-swizzled src+read.
__global__ __launch_bounds__(64) void y_step(
    const float* __restrict__ hF,
    const bf16_t* __restrict__ Ws0, const bf16_t* __restrict__ Ws1,
    const float* __restrict__ b_lin,
    float* __restrict__ yout)  // out + t*BATCH*64
{
  __shared__ __align__(16) short lWs[2 * 16 * 256];  // 16 KB

  const int mw = blockIdx.x * 16;
  const int nt = blockIdx.y;
  const int l = threadIdx.x;
  const int lr = l & 15;
  const int lq = l >> 4;

  // stage: 16 x 1KB; linear LDS dest, swizzled source
#pragma unroll
  for (int i = 0; i < 16; ++i) {
    int L = i * 1024 + l * 16;
    int plane = L >> 13;
    int R = (L >> 9) & 15;
    int c16 = L & 511;
    int csrc = c16 ^ ((R & 7) << 4);
    const bf16_t* srcrow = (plane ? Ws1 : Ws0) + (size_t)(nt * 16 + R) * HSZ;
    async16((const char*)srcrow + csrc, (char*)lWs + i * 1024);
  }
  asm volatile("s_waitcnt vmcnt(0)" ::: "memory");

  f32x4 accM = (f32x4){0.f, 0.f, 0.f, 0.f};
  f32x4 accC = (f32x4){0.f, 0.f, 0.f, 0.f};

#pragma unroll
  for (int c = 0; c < 8; ++c) {
    short8 a0, a1;
    load_cvt(hF + (size_t)(mw + lr) * HSZ + c * 32 + lq * 8, a0, a1);
    int byte = lr * 512 + ((c * 64 + lq * 16) ^ ((lr & 7) << 4));
    short8 b0 = *reinterpret_cast<const short8*>((const char*)lWs + byte);
    short8 b1 = *reinterpret_cast<const short8*>((const char*)lWs + 8192 + byte);
    accC = __builtin_amdgcn_mfma_f32_16x16x32_bf16(a0, b1, accC, 0, 0, 0);
    accC = __builtin_amdgcn_mfma_f32_16x16x32_bf16(a1, b0, accC, 0, 0, 0);
    accM = __builtin_amdgcn_mfma_f32_16x16x32_bf16(a0, b0, accM, 0, 0, 0);
  }

  const int o = nt * 16 + lr;
  const float bl = b_lin[o];
#pragma unroll
  for (int q = 0; q < 4; ++q) {
    size_t row = mw + lq * 4 + q;
    yout[row * 64 + o] = accM[q] + accC[q] + bl;
  }
}

// ---------------- BatchNorm: two-stage stats + normalize ----------------
__global__ __launch_bounds__(256) void bn_part(const float* __restrict__ Y,
                                               double* __restrict__ psum,
                                               double* __restrict__ psum2)
{
  int t = blockIdx.x;
  int chunk = blockIdx.y;
  int o = threadIdx.x & 63, rg = threadIdx.x >> 6;
  const float* Yt = Y + (size_t)t * BATCH * 64;
  int b0 = chunk * 256;
  double s = 0.0, s2 = 0.0;
  for (int b = b0 + rg; b < b0 + 256; b += 4) {
    double v = (double)Yt[(size_t)b * 64 + o];
    s += v;
    s2 += v * v;
  }
  __shared__ double ls[4][64], ls2[4][64];
  ls[rg][o] = s;
  ls2[rg][o] = s2;
  __syncthreads();
  if (rg == 0) {
    s = ls[0][o] + ls[1][o] + ls[2][o] + ls[3][o];
    s2 = ls2[0][o] + ls2[1][o] + ls2[2][o] + ls2[3][o];
    size_t pi = ((size_t)t * 16 + chunk) * 64 + o;
    psum[pi] = s;
    psum2[pi] = s2;
  }
}

__global__ __launch_bounds__(64) void bn_final(const double* __restrict__ psum,
                                               const double* __restrict__ psum2,
                                               float* __restrict__ mean,
                                               float* __restrict__ istd)
{
  int t = blockIdx.x;
  int o = threadIdx.x;
  double s = 0.0, s2 = 0.0;
  for (int c = 0; c < 16; ++c) {
    size_t pi = ((size_t)t * 16 + c) * 64 + o;
    s += psum[pi];
    s2 += psum2[pi];
  }
  double m = s * (1.0 / BATCH);
  double var = s2 * (1.0 / BATCH) - m * m;
  mean[t * 64 + o] = (float)m;
  istd[t * 64 + o] = (float)(1.0 / sqrt(var + 1e-5));
}

__global__ __launch_bounds__(256) void bn_norm(float* __restrict__ Y,
                                               const float* __restrict__ mean,
                                               const float* __restrict__ istd, int n4)
{
  for (int i = blockIdx.x * 256 + threadIdx.x; i < n4; i += gridDim.x * 256) {
    f32x4 v = reinterpret_cast<f32x4*>(Y)[i];
    int base = i * 4;
    int o = base & 63;
    int t = base >> 18;  // / (BATCH*64)
    const float* mr = mean + t * 64;
    const float* ir = istd + t * 64;
#pragma unroll
    for (int e = 0; e < 4; ++e) v[e] = (v[e] - mr[o + e]) * ir[o + e];
    reinterpret_cast<f32x4*>(Y)[i] = v;
  }
}

extern "C" void kernel_launch(void* const* d_in, const int* in_sizes, int n_in,
                              void* d_out, int out_size, void* d_ws, size_t ws_size,
                              hipStream_t stream)
{
  const float* inputs = (const float*)d_in[0];
  const float* w_ih = (const float*)d_in[1];
  const float* w_hh = (const float*)d_in[2];
  const float* b_ih = (const float*)d_in[3];
  const float* b_hh = (const float*)d_in[4];
  const float* w_lin = (const float*)d_in[5];
  const float* b_lin = (const float*)d_in[6];
  const float* u_sn = (const float*)d_in[7];
  float* out = (float*)d_out;

  const size_t BH = (size_t)BATCH * HSZ;
  const size_t BI = (size_t)BATCH * ISZ;

  char* ws = (char*)d_ws;
  size_t off = 0;
  auto alloc = [&](size_t bytes) -> void* {
    void* p = ws + off;
    off += (bytes + 255) & ~(size_t)255;
    return p;
  };
  double* w_sn_f64 = (double*)alloc((size_t)ISZ * HSZ * 8);
  bf16_t* Wi0 = (bf16_t*)alloc((size_t)3 * HSZ * ISZ * 2);
  bf16_t* Wi1 = (bf16_t*)alloc((size_t)3 * HSZ * ISZ * 2);
  bf16_t* Wh0 = (bf16_t*)alloc((size_t)3 * HSZ * HSZ * 2);
  bf16_t* Wh1 = (bf16_t*)alloc((size_t)3 * HSZ * HSZ * 2);
  bf16_t* Ws0 = (bf16_t*)alloc((size_t)ISZ * HSZ * 2);
  bf16_t* Ws1 = (bf16_t*)alloc((size_t)ISZ * HSZ * 2);
  bf16_t* X0 = (bf16_t*)alloc(BI * 2);
  bf16_t* X1 = (bf16_t*)alloc(BI * 2);
  float* hFA = (float*)alloc(BH * 4);
  float* hFB = (float*)alloc(BH * 4);
  double* psum = (double*)alloc((size_t)TSZ * 16 * 64 * 8);
  double* psum2 = (double*)alloc((size_t)TSZ * 16 * 64 * 8);
  float* meanb = (float*)alloc(TSZ * 64 * 4);
  float* istdb = (float*)alloc(TSZ * 64 * 4);
  if (off > ws_size) return;

  prep_sn<<<1, 256, 0, stream>>>(w_lin, u_sn, w_sn_f64);
  split2_f32<<<(3 * HSZ * ISZ + 255) / 256, 256, 0, stream>>>(w_ih, Wi0, Wi1, 3 * HSZ * ISZ);
  split2_f32<<<(3 * HSZ * HSZ + 255) / 256, 256, 0, stream>>>(w_hh, Wh0, Wh1, 3 * HSZ * HSZ);
  split2_f64<<<(ISZ * HSZ + 255) / 256, 256, 0, stream>>>(w_sn_f64, Ws0, Ws1, ISZ * HSZ);
  split2_f32<<<((int)BI + 255) / 256, 256, 0, stream>>>(inputs, X0, X1, (int)BI);

  // t = 0: h_0 from inputs, then y_0
  gru_first<<<dim3(BATCH / 128, 16), 256, 0, stream>>>(X0, X1, Wi0, Wi1, b_ih, b_hh, hFA);
  y_step<<<dim3(BATCH / 16, 4), 64, 0, stream>>>(hFA, Ws0, Ws1, b_lin, out);

  float* hin = hFA;
  float* hout = hFB;
  for (int t = 1; t < TSZ; ++t) {
    gru_gates<<<dim3(BATCH / 128, 16), 256, 0, stream>>>(
        out + (size_t)(t - 1) * BATCH * 64, hin,
        Wi0, Wi1, Wh0, Wh1, b_ih, b_hh, hout);
    y_step<<<dim3(BATCH / 16, 4), 64, 0, stream>>>(hout, Ws0, Ws1, b_lin,
                                                   out + (size_t)t * BATCH * 64);
    float* tm = hin; hin = hout; hout = tm;
  }

  bn_part<<<dim3(TSZ, 16), 256, 0, stream>>>(out, psum, psum2);
  bn_final<<<TSZ, 64, 0, stream>>>(psum, psum2, meanb, istdb);
  bn_norm<<<2048, 256, 0, stream>>>(out, meanb, istdb, TSZ * BATCH * 64 / 4);
}

// Round 18
// 1328.310 us; speedup vs baseline: 1.1055x; 1.1045x over previous
//
#include <hip/hip_runtime.h>
#include <hip/hip_bf16.h>

// Session rules (hard-won):
// R6: grid.sync() ~125us on MI355X -- never persistent-coop for a tight recurrence.
// R7: folding w_ih@w_sn into the recurrence fails numerically (0.139, 3x repro).
//     Only value-preserving transformations of the R5 dataflow.
// R8/R9: L2 flushed at kernel boundaries -> ~7MB/step compulsory L3 traffic.
// R9: occupancy clamp strangles VGPR; R10: compiler sinks register preloads (null).
// R12 WIN (2336->1626): global_load_lds weight staging (cold-L2 serial-load latency).
// R13 WIN (1626->1456): y_step 4-way col split. R14: fusion regressed 3rd time -- DEAD.
// R15 WIN (1456->1334): two-phase gates staging + y_step Ws burst.  <-- BEST
// R16 REGRESS (1468): gi loads after DMAs -> ordered-vmcnt drained the DMA stream.
// R17 REGRESS (1467): reg-preload+pin of gi operands -- VGPR pressure ate the overlap.
// R18: revert to R15 verbatim. Structural floor: 64 serial steps x (launch + one
//     compulsory cold-L2 staging drain + ~2.5us compute) per kernel slot.

typedef __attribute__((ext_vector_type(8))) short short8;
typedef __attribute__((ext_vector_type(4))) float f32x4;
typedef __hip_bfloat16 bf16_t;

#define BATCH 4096
#define ISZ 64
#define HSZ 256
#define TSZ 64

__device__ __forceinline__ float sigm(float x) { return 1.f / (1.f + __expf(-x)); }
__device__ __forceinline__ float tanh_fast(float x) { return 1.f - 2.f / (1.f + __expf(2.f * x)); }

// load 8 consecutive fp32 and split into two bf16 planes (in-register, RNE)
__device__ __forceinline__ void load_cvt(const float* __restrict__ p, short8& a0, short8& a1) {
  f32x4 u = *reinterpret_cast<const f32x4*>(p);
  f32x4 w = *reinterpret_cast<const f32x4*>(p + 4);
  float x[8] = {u[0], u[1], u[2], u[3], w[0], w[1], w[2], w[3]};
#pragma unroll
  for (int e = 0; e < 8; ++e) {
    bf16_t h0 = __float2bfloat16(x[e]);
    a0[e] = *reinterpret_cast<short*>(&h0);
    bf16_t h1 = __float2bfloat16(x[e] - __bfloat162float(h0));
    a1[e] = *reinterpret_cast<short*>(&h1);
  }
}

__device__ __forceinline__ void async16(const void* g, void* l) {
  __builtin_amdgcn_global_load_lds(
      (const __attribute__((address_space(1))) unsigned int*)g,
      (__attribute__((address_space(3))) unsigned int*)l, 16, 0, 0);
}

// ---------------- spectral norm prep, fp64 (1 block) ----------------
__global__ __launch_bounds__(256) void prep_sn(
    const float* __restrict__ w_lin, const float* __restrict__ u_sn,
    double* __restrict__ w_sn_f64)
{
  __shared__ double v[HSZ];
  __shared__ double red[256];
  __shared__ double Wv[ISZ];
  int t = threadIdx.x;
  double s = 0.0;
  for (int i = 0; i < ISZ; ++i) s += (double)w_lin[i * HSZ + t] * (double)u_sn[i];
  red[t] = s * s;
  __syncthreads();
  for (int off = 128; off > 0; off >>= 1) { if (t < off) red[t] += red[t + off]; __syncthreads(); }
  double nv = sqrt(red[0]);
  v[t] = s / (nv + 1e-12);
  __syncthreads();
  {
    int i = t >> 2, p = t & 3;
    double ps = 0.0;
    for (int k = p * 64; k < p * 64 + 64; ++k) ps += (double)w_lin[i * HSZ + k] * v[k];
    red[t] = ps;
    __syncthreads();
    if ((t & 3) == 0) Wv[i] = red[t] + red[t + 1] + red[t + 2] + red[t + 3];
    __syncthreads();
  }
  red[t] = (t < ISZ) ? Wv[t] * Wv[t] : 0.0;
  __syncthreads();
  for (int off = 128; off > 0; off >>= 1) { if (t < off) red[t] += red[t + off]; __syncthreads(); }
  double nw = sqrt(red[0]);
  double sigma = red[0] / (nw + 1e-12);  // u.(Wv), u = Wv/(|Wv|+eps)
  double inv_sigma = 1.0 / sigma;
  for (int idx = t; idx < ISZ * HSZ; idx += 256)
    w_sn_f64[idx] = (double)w_lin[idx] * inv_sigma;
}

// ---------------- 2-plane split casts (weights + t=0 inputs) ----------------
__global__ __launch_bounds__(256) void split2_f32(
    const float* __restrict__ x, bf16_t* __restrict__ p0, bf16_t* __restrict__ p1, int n)
{
  int i = blockIdx.x * 256 + threadIdx.x;
  if (i < n) {
    float v = x[i];
    bf16_t a = __float2bfloat16(v);
    p0[i] = a;
    p1[i] = __float2bfloat16(v - __bfloat162float(a));
  }
}

__global__ __launch_bounds__(256) void split2_f64(
    const double* __restrict__ x, bf16_t* __restrict__ p0, bf16_t* __restrict__ p1, int n)
{
  int i = blockIdx.x * 256 + threadIdx.x;
  if (i < n) {
    double v = x[i];
    bf16_t a = __float2bfloat16((float)v);
    p0[i] = a;
    p1[i] = __float2bfloat16((float)(v - (double)__bfloat162float(a)));
  }
}

// ---------------- t=0: gi from inputs, h1 = (1-z)*n -> fp32 ----------------
__global__ __launch_bounds__(256) void gru_first(
    const bf16_t* __restrict__ X0, const bf16_t* __restrict__ X1,
    const bf16_t* __restrict__ Wi0, const bf16_t* __restrict__ Wi1,
    const float* __restrict__ b_ih, const float* __restrict__ b_hh,
    float* __restrict__ hF)
{
  const int jb = blockIdx.y;
  const int mw = blockIdx.x * 128 + (threadIdx.x >> 6) * 32;
  const int l = threadIdx.x & 63;
  const int lr = l & 15;
  const int lq = l >> 4;
  const int j = jb * 16 + lr;

  f32x4 accM[2][3], accC[2][3];
#pragma unroll
  for (int mt = 0; mt < 2; ++mt)
#pragma unroll
    for (int g = 0; g < 3; ++g) {
      accM[mt][g] = (f32x4){0.f, 0.f, 0.f, 0.f};
      accC[mt][g] = (f32x4){0.f, 0.f, 0.f, 0.f};
    }

#pragma unroll
  for (int kk = 0; kk < ISZ; kk += 32) {
    short8 a0[2], a1[2];
#pragma unroll
    for (int mt = 0; mt < 2; ++mt) {
      size_t ao = (size_t)(mw + mt * 16 + lr) * ISZ + kk + lq * 8;
      a0[mt] = *reinterpret_cast<const short8*>(X0 + ao);
      a1[mt] = *reinterpret_cast<const short8*>(X1 + ao);
    }
#pragma unroll
    for (int g = 0; g < 3; ++g) {
      size_t bo = (size_t)(g * HSZ + jb * 16 + lr) * ISZ + kk + lq * 8;
      short8 b0 = *reinterpret_cast<const short8*>(Wi0 + bo);
      short8 b1 = *reinterpret_cast<const short8*>(Wi1 + bo);
#pragma unroll
      for (int mt = 0; mt < 2; ++mt) {
        accC[mt][g] = __builtin_amdgcn_mfma_f32_16x16x32_bf16(a0[mt], b1, accC[mt][g], 0, 0, 0);
        accC[mt][g] = __builtin_amdgcn_mfma_f32_16x16x32_bf16(a1[mt], b0, accC[mt][g], 0, 0, 0);
        accM[mt][g] = __builtin_amdgcn_mfma_f32_16x16x32_bf16(a0[mt], b0, accM[mt][g], 0, 0, 0);
      }
    }
  }

  const float brz = b_ih[j] + b_hh[j];
  const float bzz = b_ih[HSZ + j] + b_hh[HSZ + j];
  const float bin = b_ih[2 * HSZ + j];
  const float bhn = b_hh[2 * HSZ + j];

#pragma unroll
  for (int mt = 0; mt < 2; ++mt) {
#pragma unroll
    for (int q = 0; q < 4; ++q) {
      int b = mw + mt * 16 + lq * 4 + q;
      float r = sigm(accM[mt][0][q] + accC[mt][0][q] + brz);
      float z = sigm(accM[mt][1][q] + accC[mt][1][q] + bzz);
      float n = tanh_fast(accM[mt][2][q] + accC[mt][2][q] + bin + r * bhn);
      hF[(size_t)b * HSZ + j] = (1.f - z) * n;
    }
  }
}

// ---------------- gates step (t>=1): two-phase counted staging ----------------
// Grid (BATCH/128, 16); block 256 = 4 waves; wave = 32 rows (2 mt) x 16 j.
// Phase A: stage Wi (3 DMA) -> vmcnt(0) + raw barrier -> issue Wh (12 DMA) + holds
//          -> gi from lWi (Wh streams underneath).
// Phase B: vmcnt(0) + raw barrier -> gh from lWh.
// XOR swizzle byte ^= (R&7)<<4 on global SOURCE + ds_read (rule #21).
__global__ __launch_bounds__(256) void gru_gates(
    const float* __restrict__ yprev,  // out + (t-1)*BATCH*64
    const float* __restrict__ hF,     // [BATCH, 256] fp32
    const bf16_t* __restrict__ Wi0, const bf16_t* __restrict__ Wi1,
    const bf16_t* __restrict__ Wh0, const bf16_t* __restrict__ Wh1,
    const float* __restrict__ b_ih, const float* __restrict__ b_hh,
    float* __restrict__ hFo)
{
  __shared__ __align__(16) short lWh[96 * 256];  // 48 KB
  __shared__ __align__(16) short lWi[96 * 64];   // 12 KB

  const int jb = blockIdx.y;
  const int tid = threadIdx.x;
  const int wid = tid >> 6;
  const int mw = blockIdx.x * 128 + wid * 32;
  const int l = tid & 63;
  const int lr = l & 15;
  const int lq = l >> 4;
  const int j = jb * 16 + lr;

  // ---- phase A1: stage Wi (3 x 4KB)
#pragma unroll
  for (int i = 0; i < 3; ++i) {
    int L = i * 4096 + tid * 16;
    int R = L >> 7, c16 = L & 127;
    int csrc = c16 ^ ((R & 7) << 4);
    int g = R >> 5, p = (R >> 4) & 1, jr = R & 15;
    const bf16_t* srcrow = (p ? Wi1 : Wi0) + (size_t)(g * HSZ + jb * 16 + jr) * ISZ;
    async16((const char*)srcrow + csrc, (char*)lWi + i * 4096 + wid * 1024);
  }
  asm volatile("s_waitcnt vmcnt(0)" ::: "memory");
  __builtin_amdgcn_s_barrier();

  // ---- phase A2: issue Wh (12 x 4KB) -- completes during gi
#pragma unroll
  for (int i = 0; i < 12; ++i) {
    int L = i * 4096 + tid * 16;
    int R = L >> 9, c16 = L & 511;
    int csrc = c16 ^ ((R & 7) << 4);
    int g = R >> 5, p = (R >> 4) & 1, jr = R & 15;
    const bf16_t* srcrow = (p ? Wh1 : Wh0) + (size_t)(g * HSZ + jb * 16 + jr) * HSZ;
    async16((const char*)srcrow + csrc, (char*)lWh + i * 4096 + wid * 1024);
  }

  // hold loads (overlap with Wh streaming)
  float hold_[2][4];
#pragma unroll
  for (int mt = 0; mt < 2; ++mt)
#pragma unroll
    for (int q = 0; q < 4; ++q)
      hold_[mt][q] = hF[(size_t)(mw + mt * 16 + lq * 4 + q) * HSZ + j];

  f32x4 accM[2][4], accC[2][4];
#pragma unroll
  for (int mt = 0; mt < 2; ++mt)
#pragma unroll
    for (int g = 0; g < 4; ++g) {
      accM[mt][g] = (f32x4){0.f, 0.f, 0.f, 0.f};
      accC[mt][g] = (f32x4){0.f, 0.f, 0.f, 0.f};
    }

  auto whf = [&](int g, int p, int c) -> short8 {
    int R = (g * 2 + p) * 16 + lr;
    int byte = R * 512 + ((c * 64 + lq * 16) ^ ((lr & 7) << 4));
    return *reinterpret_cast<const short8*>((const char*)lWh + byte);
  };
  auto wif = [&](int g, int p, int c) -> short8 {
    int R = (g * 2 + p) * 16 + lr;
    int byte = R * 128 + ((c * 64 + lq * 16) ^ ((lr & 7) << 4));
    return *reinterpret_cast<const short8*>((const char*)lWi + byte);
  };

  // ---- gi: x = split2(yprev) @ w_ih.T (K=64); gates 0,1,2 -> cols 0,1,2
#pragma unroll
  for (int c = 0; c < 2; ++c) {
    short8 a0[2], a1[2];
#pragma unroll
    for (int mt = 0; mt < 2; ++mt)
      load_cvt(yprev + (size_t)(mw + mt * 16 + lr) * ISZ + c * 32 + lq * 8, a0[mt], a1[mt]);
#pragma unroll
    for (int g = 0; g < 3; ++g) {
      short8 b0 = wif(g, 0, c);
      short8 b1 = wif(g, 1, c);
#pragma unroll
      for (int mt = 0; mt < 2; ++mt) {
        accC[mt][g] = __builtin_amdgcn_mfma_f32_16x16x32_bf16(a0[mt], b1, accC[mt][g], 0, 0, 0);
        accC[mt][g] = __builtin_amdgcn_mfma_f32_16x16x32_bf16(a1[mt], b0, accC[mt][g], 0, 0, 0);
        accM[mt][g] = __builtin_amdgcn_mfma_f32_16x16x32_bf16(a0[mt], b0, accM[mt][g], 0, 0, 0);
      }
    }
  }

  // ---- phase B: wait Wh, then gh
  asm volatile("s_waitcnt vmcnt(0)" ::: "memory");
  __builtin_amdgcn_s_barrier();

  // gh: h = split2(hF) @ w_hh.T (K=256); gates 0,1 -> cols 0,1; gate 2 -> col 3
#pragma unroll
  for (int c = 0; c < 8; ++c) {
    short8 a0[2], a1[2];
#pragma unroll
    for (int mt = 0; mt < 2; ++mt)
      load_cvt(hF + (size_t)(mw + mt * 16 + lr) * HSZ + c * 32 + lq * 8, a0[mt], a1[mt]);
#pragma unroll
    for (int g = 0; g < 3; ++g) {
      const int tgt = (g == 2) ? 3 : g;
      short8 b0 = whf(g, 0, c);
      short8 b1 = whf(g, 1, c);
#pragma unroll
      for (int mt = 0; mt < 2; ++mt) {
        accC[mt][tgt] = __builtin_amdgcn_mfma_f32_16x16x32_bf16(a0[mt], b1, accC[mt][tgt], 0, 0, 0);
        accC[mt][tgt] = __builtin_amdgcn_mfma_f32_16x16x32_bf16(a1[mt], b0, accC[mt][tgt], 0, 0, 0);
        accM[mt][tgt] = __builtin_amdgcn_mfma_f32_16x16x32_bf16(a0[mt], b0, accM[mt][tgt], 0, 0, 0);
      }
    }
  }

  const float brz = b_ih[j] + b_hh[j];
  const float bzz = b_ih[HSZ + j] + b_hh[HSZ + j];
  const float bin = b_ih[2 * HSZ + j];
  const float bhn = b_hh[2 * HSZ + j];

#pragma unroll
  for (int mt = 0; mt < 2; ++mt) {
#pragma unroll
    for (int q = 0; q < 4; ++q) {
      int b = mw + mt * 16 + lq * 4 + q;  // C/D: row=(lane>>4)*4+reg, col=lane&15
      float rpre = accM[mt][0][q] + accC[mt][0][q] + brz;
      float zpre = accM[mt][1][q] + accC[mt][1][q] + bzz;
      float inn  = accM[mt][2][q] + accC[mt][2][q] + bin;
      float hnn  = accM[mt][3][q] + accC[mt][3][q] + bhn;
      float r = sigm(rpre);
      float z = sigm(zpre);
      float n = tanh_fast(inn + r * hnn);
      double hv = (double)((1.f - z) * n) + (double)z * (double)hold_[mt][q];
      hFo[(size_t)b * HSZ + j] = (float)hv;
    }
  }
}

// ---------------- y_step: out[t] = split2(hF) @ w_sn.T + b_lin ----------------
// Grid (BATCH/16, 4) one-wave blocks; wave = 16 rows x one 16-col tile (nt).
// Ws slice (16 KB) staged via global_load_lds burst; XOR-swizzled src+read.
__global__ __launch_bounds__(64) void y_step(
    const float* __restrict__ hF,
    const bf16_t* __restrict__ Ws0, const bf16_t* __restrict__ Ws1,
    const float* __restrict__ b_lin,
    float* __restrict__ yout)  // out + t*BATCH*64
{
  __shared__ __align__(16) short lWs[2 * 16 * 256];  // 16 KB

  const int mw = blockIdx.x * 16;
  const int nt = blockIdx.y;
  const int l = threadIdx.x;
  const int lr = l & 15;
  const int lq = l >> 4;

  // stage: 16 x 1KB; linear LDS dest, swizzled source
#pragma unroll
  for (int i = 0; i < 16; ++i) {
    int L = i * 1024 + l * 16;
    int plane = L >> 13;
    int R = (L >> 9) & 15;
    int c16 = L & 511;
    int csrc = c16 ^ ((R & 7) << 4);
    const bf16_t* srcrow = (plane ? Ws1 : Ws0) + (size_t)(nt * 16 + R) * HSZ;
    async16((const char*)srcrow + csrc, (char*)lWs + i * 1024);
  }
  asm volatile("s_waitcnt vmcnt(0)" ::: "memory");

  f32x4 accM = (f32x4){0.f, 0.f, 0.f, 0.f};
  f32x4 accC = (f32x4){0.f, 0.f, 0.f, 0.f};

#pragma unroll
  for (int c = 0; c < 8; ++c) {
    short8 a0, a1;
    load_cvt(hF + (size_t)(mw + lr) * HSZ + c * 32 + lq * 8, a0, a1);
    int byte = lr * 512 + ((c * 64 + lq * 16) ^ ((lr & 7) << 4));
    short8 b0 = *reinterpret_cast<const short8*>((const char*)lWs + byte);
    short8 b1 = *reinterpret_cast<const short8*>((const char*)lWs + 8192 + byte);
    accC = __builtin_amdgcn_mfma_f32_16x16x32_bf16(a0, b1, accC, 0, 0, 0);
    accC = __builtin_amdgcn_mfma_f32_16x16x32_bf16(a1, b0, accC, 0, 0, 0);
    accM = __builtin_amdgcn_mfma_f32_16x16x32_bf16(a0, b0, accM, 0, 0, 0);
  }

  const int o = nt * 16 + lr;
  const float bl = b_lin[o];
#pragma unroll
  for (int q = 0; q < 4; ++q) {
    size_t row = mw + lq * 4 + q;
    yout[row * 64 + o] = accM[q] + accC[q] + bl;
  }
}

// ---------------- BatchNorm: two-stage stats + normalize ----------------
__global__ __launch_bounds__(256) void bn_part(const float* __restrict__ Y,
                                               double* __restrict__ psum,
                                               double* __restrict__ psum2)
{
  int t = blockIdx.x;
  int chunk = blockIdx.y;
  int o = threadIdx.x & 63, rg = threadIdx.x >> 6;
  const float* Yt = Y + (size_t)t * BATCH * 64;
  int b0 = chunk * 256;
  double s = 0.0, s2 = 0.0;
  for (int b = b0 + rg; b < b0 + 256; b += 4) {
    double v = (double)Yt[(size_t)b * 64 + o];
    s += v;
    s2 += v * v;
  }
  __shared__ double ls[4][64], ls2[4][64];
  ls[rg][o] = s;
  ls2[rg][o] = s2;
  __syncthreads();
  if (rg == 0) {
    s = ls[0][o] + ls[1][o] + ls[2][o] + ls[3][o];
    s2 = ls2[0][o] + ls2[1][o] + ls2[2][o] + ls2[3][o];
    size_t pi = ((size_t)t * 16 + chunk) * 64 + o;
    psum[pi] = s;
    psum2[pi] = s2;
  }
}

__global__ __launch_bounds__(64) void bn_final(const double* __restrict__ psum,
                                               const double* __restrict__ psum2,
                                               float* __restrict__ mean,
                                               float* __restrict__ istd)
{
  int t = blockIdx.x;
  int o = threadIdx.x;
  double s = 0.0, s2 = 0.0;
  for (int c = 0; c < 16; ++c) {
    size_t pi = ((size_t)t * 16 + c) * 64 + o;
    s += psum[pi];
    s2 += psum2[pi];
  }
  double m = s * (1.0 / BATCH);
  double var = s2 * (1.0 / BATCH) - m * m;
  mean[t * 64 + o] = (float)m;
  istd[t * 64 + o] = (float)(1.0 / sqrt(var + 1e-5));
}

__global__ __launch_bounds__(256) void bn_norm(float* __restrict__ Y,
                                               const float* __restrict__ mean,
                                               const float* __restrict__ istd, int n4)
{
  for (int i = blockIdx.x * 256 + threadIdx.x; i < n4; i += gridDim.x * 256) {
    f32x4 v = reinterpret_cast<f32x4*>(Y)[i];
    int base = i * 4;
    int o = base & 63;
    int t = base >> 18;  // / (BATCH*64)
    const float* mr = mean + t * 64;
    const float* ir = istd + t * 64;
#pragma unroll
    for (int e = 0; e < 4; ++e) v[e] = (v[e] - mr[o + e]) * ir[o + e];
    reinterpret_cast<f32x4*>(Y)[i] = v;
  }
}

extern "C" void kernel_launch(void* const* d_in, const int* in_sizes, int n_in,
                              void* d_out, int out_size, void* d_ws, size_t ws_size,
                              hipStream_t stream)
{
  const float* inputs = (const float*)d_in[0];
  const float* w_ih = (const float*)d_in[1];
  const float* w_hh = (const float*)d_in[2];
  const float* b_ih = (const float*)d_in[3];
  const float* b_hh = (const float*)d_in[4];
  const float* w_lin = (const float*)d_in[5];
  const float* b_lin = (const float*)d_in[6];
  const float* u_sn = (const float*)d_in[7];
  float* out = (float*)d_out;

  const size_t BH = (size_t)BATCH * HSZ;
  const size_t BI = (size_t)BATCH * ISZ;

  char* ws = (char*)d_ws;
  size_t off = 0;
  auto alloc = [&](size_t bytes) -> void* {
    void* p = ws + off;
    off += (bytes + 255) & ~(size_t)255;
    return p;
  };
  double* w_sn_f64 = (double*)alloc((size_t)ISZ * HSZ * 8);
  bf16_t* Wi0 = (bf16_t*)alloc((size_t)3 * HSZ * ISZ * 2);
  bf16_t* Wi1 = (bf16_t*)alloc((size_t)3 * HSZ * ISZ * 2);
  bf16_t* Wh0 = (bf16_t*)alloc((size_t)3 * HSZ * HSZ * 2);
  bf16_t* Wh1 = (bf16_t*)alloc((size_t)3 * HSZ * HSZ * 2);
  bf16_t* Ws0 = (bf16_t*)alloc((size_t)ISZ * HSZ * 2);
  bf16_t* Ws1 = (bf16_t*)alloc((size_t)ISZ * HSZ * 2);
  bf16_t* X0 = (bf16_t*)alloc(BI * 2);
  bf16_t* X1 = (bf16_t*)alloc(BI * 2);
  float* hFA = (float*)alloc(BH * 4);
  float* hFB = (float*)alloc(BH * 4);
  double* psum = (double*)alloc((size_t)TSZ * 16 * 64 * 8);
  double* psum2 = (double*)alloc((size_t)TSZ * 16 * 64 * 8);
  float* meanb = (float*)alloc(TSZ * 64 * 4);
  float* istdb = (float*)alloc(TSZ * 64 * 4);
  if (off > ws_size) return;

  prep_sn<<<1, 256, 0, stream>>>(w_lin, u_sn, w_sn_f64);
  split2_f32<<<(3 * HSZ * ISZ + 255) / 256, 256, 0, stream>>>(w_ih, Wi0, Wi1, 3 * HSZ * ISZ);
  split2_f32<<<(3 * HSZ * HSZ + 255) / 256, 256, 0, stream>>>(w_hh, Wh0, Wh1, 3 * HSZ * HSZ);
  split2_f64<<<(ISZ * HSZ + 255) / 256, 256, 0, stream>>>(w_sn_f64, Ws0, Ws1, ISZ * HSZ);
  split2_f32<<<((int)BI + 255) / 256, 256, 0, stream>>>(inputs, X0, X1, (int)BI);

  // t = 0: h_0 from inputs, then y_0
  gru_first<<<dim3(BATCH / 128, 16), 256, 0, stream>>>(X0, X1, Wi0, Wi1, b_ih, b_hh, hFA);
  y_step<<<dim3(BATCH / 16, 4), 64, 0, stream>>>(hFA, Ws0, Ws1, b_lin, out);

  float* hin = hFA;
  float* hout = hFB;
  for (int t = 1; t < TSZ; ++t) {
    gru_gates<<<dim3(BATCH / 128, 16), 256, 0, stream>>>(
        out + (size_t)(t - 1) * BATCH * 64, hin,
        Wi0, Wi1, Wh0, Wh1, b_ih, b_hh, hout);
    y_step<<<dim3(BATCH / 16, 4), 64, 0, stream>>>(hout, Ws0, Ws1, b_lin,
                                                   out + (size_t)t * BATCH * 64);
    float* tm = hin; hin = hout; hout = tm;
  }

  bn_part<<<dim3(TSZ, 16), 256, 0, stream>>>(out, psum, psum2);
  bn_final<<<TSZ, 64, 0, stream>>>(psum, psum2, meanb, istdb);
  bn_norm<<<2048, 256, 0, stream>>>(out, meanb, istdb, TSZ * BATCH * 64 / 4);
}